// Round 8
// baseline (648.884 us; speedup 1.0000x reference)
//
#include <hip/hip_runtime.h>
#include <hip/hip_bf16.h>
#include <hip/hip_cooperative_groups.h>

namespace cg = cooperative_groups;

// Problem constants (QuadraticAttention): B=2, T=2048, D_MODEL=1024, H=16, d=64
#define TSEQ   2048
#define DM     1024
#define NHEAD  16
#define DH     64
#define BATCH  2
#define MR     (BATCH * TSEQ)   // 4096 rows
#define CH     64               // attention chunk length
#define NC     (TSEQ / CH)      // 32 chunks per sequence
#define QKVLD  (3 * DM)         // 3072 fused N
#define LP     72               // padded LDS row stride (bf16)
#define SMEMB  18432            // shared arena bytes (max over phases)

typedef __attribute__((ext_vector_type(8))) short bf16x8;
typedef __attribute__((ext_vector_type(4))) float f32x4;

__device__ __forceinline__ short f2bf(float x) {
  __hip_bfloat16 h = __float2bfloat16(x);
  return *reinterpret_cast<short*>(&h);
}

__device__ __forceinline__ void stage16(const void* g, void* l) {
  __builtin_amdgcn_global_load_lds(
      (const __attribute__((address_space(1))) void*)g,
      (__attribute__((address_space(3))) void*)l, 16, 0, 0);
}

// ============================================================================
// Phase bodies as __device__ functions — shared by the fused cooperative
// kernel and the standalone fallback kernels (one body to trust).
// ============================================================================

// ---- P0: prep. u in [0,1280): z=u>>8 selects W0..W3 transpose or x->bf16 ----
__device__ __forceinline__ void dev_prep_unit(
    int u, const float* __restrict__ x, const float* __restrict__ Wq,
    const float* __restrict__ Wk, const float* __restrict__ Wv,
    const float* __restrict__ Wo, short* __restrict__ xb,
    short* __restrict__ WtAll, char* smem) {
  const int tid = threadIdx.x;
  __syncthreads();   // LDS WAR vs previous unit/phase
  const int z = u >> 8, wv = u & 255;
  if (z == 4) {
    const float* src = x + (size_t)wv * 16384;
    short* dst = xb + (size_t)wv * 16384;
#pragma unroll
    for (int it = 0; it < 16; ++it) {
      int i = it * 1024 + tid * 4;
      float4 v = *(const float4*)(src + i);
      union { short h[4]; uint2 uu; } pk;
      pk.h[0] = f2bf(v.x); pk.h[1] = f2bf(v.y);
      pk.h[2] = f2bf(v.z); pk.h[3] = f2bf(v.w);
      *(uint2*)(dst + i) = pk.uu;
    }
  } else {
    const int bx = wv & 15, by = wv >> 4;
    const float* W = z == 0 ? Wq : z == 1 ? Wk : z == 2 ? Wv : Wo;
    short* o = WtAll + (size_t)z * DM * DM;
    float (*tile)[65] = (float(*)[65])smem;   // 16.6 KB
    const int kt = by * 64, nt = bx * 64;
    const int lr = tid >> 6, lc = tid & 63;
#pragma unroll
    for (int i = 0; i < 16; ++i) {
      int k = i * 4 + lr;
      tile[k][lc] = W[(size_t)(kt + k) * DM + nt + lc];
    }
    __syncthreads();
    const int nl = tid >> 4, k4 = (tid & 15) * 4;
#pragma unroll
    for (int i = 0; i < 4; ++i) {
      int n = i * 16 + nl;
      union { short h[4]; uint2 uu; } pk;
#pragma unroll
      for (int xx = 0; xx < 4; ++xx) pk.h[xx] = f2bf(tile[k4 + xx][n]);
      *(uint2*)(o + (size_t)(nt + n) * DM + kt + k4) = pk.uu;
    }
  }
}

// ---- P1: fused QKV GEMM tile (R4 proven body). bx in [0,24), by in [0,32) --
__device__ __forceinline__ void dev_qkv_tile(
    int bx, int by, const short* __restrict__ A, const short* __restrict__ Bt,
    short* __restrict__ qb, short* __restrict__ kb,
    short* __restrict__ kT, short* __restrict__ vT, char* smem) {
  const int K = DM;
  short (*As)[32] = (short(*)[32])smem;            // 8 KB
  short (*Bs)[32] = (short(*)[32])(smem + 8192);   // 8 KB
  const int tid = threadIdx.x, lane = tid & 63, wid = tid >> 6;
  const int wave_m = wid >> 1, wave_n = wid & 1;
  const int row0 = by * 128, col0 = bx * 128;

  const int sr = tid >> 2, sk = (tid & 3) * 8;
  const short* Ag0 = A + (size_t)(row0 + sr) * K + sk;
  const short* Bg0 = Bt + (size_t)(col0 + sr) * K + sk;
  short* AsL = &As[0][0] + tid * 8;
  short* BsL = &Bs[0][0] + tid * 8;

  f32x4 acc[4][4];
#pragma unroll
  for (int i = 0; i < 4; ++i)
#pragma unroll
    for (int j = 0; j < 4; ++j) acc[i][j] = (f32x4){0.f, 0.f, 0.f, 0.f};

  const int fm = wave_m * 64 + (lane & 15);
  const int fn = wave_n * 64 + (lane & 15);
  const int fk = (lane >> 4) * 8;

  __syncthreads();   // LDS WAR vs previous tile/phase
  for (int k0 = 0; k0 < K; k0 += 32) {
    stage16(Ag0 + k0, AsL);
    stage16(Ag0 + (size_t)64 * K + k0, AsL + 2048);
    stage16(Bg0 + k0, BsL);
    stage16(Bg0 + (size_t)64 * K + k0, BsL + 2048);
    __syncthreads();
    bf16x8 af[4], bf[4];
#pragma unroll
    for (int t = 0; t < 4; ++t) {
      af[t] = *(const bf16x8*)&As[fm + t * 16][fk];
      bf[t] = *(const bf16x8*)&Bs[fn + t * 16][fk];
    }
#pragma unroll
    for (int im = 0; im < 4; ++im)
#pragma unroll
      for (int jn = 0; jn < 4; ++jn)
        acc[im][jn] = __builtin_amdgcn_mfma_f32_16x16x32_bf16(af[im], bf[jn], acc[im][jn], 0, 0, 0);
    __syncthreads();
  }

  const int crow = (lane >> 4) * 4, ccol = lane & 15;
  const int region = col0 >> 10;   // 0=Q, 1=K, 2=V

  if (region <= 1) {
    short* Cb = (region == 0) ? qb : kb;
#pragma unroll
    for (int im = 0; im < 4; ++im)
#pragma unroll
      for (int jn = 0; jn < 4; ++jn) {
        const int gr = row0 + wave_m * 64 + im * 16 + crow;
        const int gc = (col0 & 1023) + wave_n * 64 + jn * 16 + ccol;
        short* Cp = Cb + (size_t)gr * DM + gc;
#pragma unroll
        for (int r = 0; r < 4; ++r) Cp[(size_t)r * DM] = f2bf(acc[im][jn][r]);
      }
  }
  if (region >= 1) {
    short* Tt = (region == 1) ? kT : vT;
    const int gr0 = row0 + wave_m * 64;   // chunk-aligned (64 rows)
    const int b = gr0 >> 11;
    const int c = (gr0 & 2047) >> 6;
#pragma unroll
    for (int im = 0; im < 4; ++im)
#pragma unroll
      for (int jn = 0; jn < 4; ++jn) {
        const int gcol = (col0 & 1023) + wave_n * 64 + jn * 16 + ccol;
        const int h = gcol >> 6, i = gcol & 63;
        const int s0 = im * 16 + crow;
        size_t idx = ((((size_t)(b * NHEAD + h) * NC + c) * DH + i) * DH + s0);
        union { short h4[4]; uint2 uu; } pk;
#pragma unroll
        for (int r = 0; r < 4; ++r) pk.h4[r] = f2bf(acc[im][jn][r]);
        *(uint2*)(Tt + idx) = pk.uu;
      }
  }
}

// ---- P2: exclusive state scan. u in [0,128) -------------------------------
__device__ __forceinline__ void dev_state_unit(
    int u, const short* __restrict__ kT, const short* __restrict__ vT,
    short* __restrict__ Spre) {
  const int js = u & 3, h = (u >> 2) & 15, b = u >> 6;
  const int tid = threadIdx.x, lane = tid & 63, w = tid >> 6;
  const int m = lane & 15, q = lane >> 4;
  const size_t hbase = ((size_t)(b * NHEAD + h) * NC) * (DH * DH);
  const int jrow = 16 * js + m;
  const int irow = 16 * w + m;
  f32x4 run = (f32x4){0.f, 0.f, 0.f, 0.f};
  for (int c = 0; c < NC; ++c) {
    const size_t tile = hbase + (size_t)c * (DH * DH);
#pragma unroll
    for (int rr = 0; rr < 4; ++rr)
      Spre[tile + (size_t)(16 * js + q * 4 + rr) * DH + 16 * w + m] = f2bf(run[rr]);
    bf16x8 a0 = *(const bf16x8*)(vT + tile + (size_t)jrow * DH + q * 8);
    bf16x8 a1 = *(const bf16x8*)(vT + tile + (size_t)jrow * DH + q * 8 + 32);
    bf16x8 b0 = *(const bf16x8*)(kT + tile + (size_t)irow * DH + q * 8);
    bf16x8 b1 = *(const bf16x8*)(kT + tile + (size_t)irow * DH + q * 8 + 32);
    f32x4 t = (f32x4){0.f, 0.f, 0.f, 0.f};
    t = __builtin_amdgcn_mfma_f32_16x16x32_bf16(a0, b0, t, 0, 0, 0);
    t = __builtin_amdgcn_mfma_f32_16x16x32_bf16(a1, b1, t, 0, 0, 0);
    run += t;
  }
}

// ---- P3: intra-chunk attention. u in [0,1024) -----------------------------
__device__ __forceinline__ void dev_intra_unit(
    int u, const short* __restrict__ qb, const short* __restrict__ kb,
    const short* __restrict__ vT, const short* __restrict__ Spre,
    short* __restrict__ aob, char* smem) {
  const int c = u & 31, h = (u >> 5) & 15, b = u >> 9;
  short (*Qs)[LP] = (short(*)[LP])smem;            // 9.2 KB
  short (*Ks)[LP] = (short(*)[LP])(smem + 9216);   // 9.2 KB
  const int tid = threadIdx.x, lane = tid & 63, w = tid >> 6;
  const int m = lane & 15, q = lane >> 4;
  const int r = tid >> 2, q16 = (tid & 3) * 16;
  const size_t tile = ((size_t)(b * NHEAD + h) * NC + c) * (DH * DH);
  const size_t grow = ((size_t)(b * TSEQ + c * CH + r)) * DM + h * DH;
  __syncthreads();   // LDS WAR vs previous unit/phase
  *(bf16x8*)&Qs[r][q16]     = *(const bf16x8*)(qb + grow + q16);
  *(bf16x8*)&Qs[r][q16 + 8] = *(const bf16x8*)(qb + grow + q16 + 8);
  *(bf16x8*)&Ks[r][q16]     = *(const bf16x8*)(kb + grow + q16);
  *(bf16x8*)&Ks[r][q16 + 8] = *(const bf16x8*)(kb + grow + q16 + 8);
  const short* vt = vT + tile;
  const short* st = Spre + tile;
  bf16x8 av0 = *(const bf16x8*)(vt + (16 * w + m) * DH + q * 8);
  bf16x8 av1 = *(const bf16x8*)(vt + (16 * w + m) * DH + q * 8 + 32);
  bf16x8 as0 = *(const bf16x8*)(st + (16 * w + m) * DH + q * 8);
  bf16x8 as1 = *(const bf16x8*)(st + (16 * w + m) * DH + q * 8 + 32);
  __syncthreads();

  bf16x8 aq0 = *(const bf16x8*)&Qs[16 * w + m][q * 8];
  bf16x8 aq1 = *(const bf16x8*)&Qs[16 * w + m][q * 8 + 32];

  f32x4 acc[4], pacc[4];
#pragma unroll
  for (int ct = 0; ct < 4; ++ct) {
    acc[ct] = (f32x4){0.f, 0.f, 0.f, 0.f};
    pacc[ct] = (f32x4){0.f, 0.f, 0.f, 0.f};
  }
#pragma unroll
  for (int ct = 0; ct < 4; ++ct) {
    bf16x8 bq0 = *(const bf16x8*)&Qs[ct * 16 + m][q * 8];
    bf16x8 bq1 = *(const bf16x8*)&Qs[ct * 16 + m][q * 8 + 32];
    acc[ct] = __builtin_amdgcn_mfma_f32_16x16x32_bf16(as0, bq0, acc[ct], 0, 0, 0);
    acc[ct] = __builtin_amdgcn_mfma_f32_16x16x32_bf16(as1, bq1, acc[ct], 0, 0, 0);
    bf16x8 bk0 = *(const bf16x8*)&Ks[ct * 16 + m][q * 8];
    bf16x8 bk1 = *(const bf16x8*)&Ks[ct * 16 + m][q * 8 + 32];
    pacc[ct] = __builtin_amdgcn_mfma_f32_16x16x32_bf16(aq0, bk0, pacc[ct], 0, 0, 0);
    pacc[ct] = __builtin_amdgcn_mfma_f32_16x16x32_bf16(aq1, bk1, pacc[ct], 0, 0, 0);
  }
  __syncthreads();
#pragma unroll
  for (int ct = 0; ct < 4; ++ct) {
    const int s = ct * 16 + m;
#pragma unroll
    for (int rr = 0; rr < 4; ++rr) {
      const int t = 16 * w + q * 4 + rr;
      Ks[t][s] = f2bf((s < t) ? pacc[ct][rr] : 0.f);
    }
  }
  __syncthreads();
#pragma unroll
  for (int ct = 0; ct < 4; ++ct) {
    bf16x8 bp0 = *(const bf16x8*)&Ks[ct * 16 + m][q * 8];
    bf16x8 bp1 = *(const bf16x8*)&Ks[ct * 16 + m][q * 8 + 32];
    acc[ct] = __builtin_amdgcn_mfma_f32_16x16x32_bf16(av0, bp0, acc[ct], 0, 0, 0);
    acc[ct] = __builtin_amdgcn_mfma_f32_16x16x32_bf16(av1, bp1, acc[ct], 0, 0, 0);
  }
#pragma unroll
  for (int ct = 0; ct < 4; ++ct) {
    const int t = ct * 16 + m, j0 = 16 * w + q * 4;
    union { short h4[4]; uint2 uu; } pk;
#pragma unroll
    for (int rr = 0; rr < 4; ++rr) pk.h4[rr] = f2bf(acc[ct][rr]);
    *(uint2*)(aob + ((size_t)(b * TSEQ + c * CH + t)) * DM + h * DH + j0) = pk.uu;
  }
}

// ---- P4: output projection tile. bx in [0,16), by in [0,32) ---------------
__device__ __forceinline__ void dev_out_tile(
    int bx, int by, const short* __restrict__ A, const short* __restrict__ Bt,
    float* __restrict__ C, char* smem) {
  const int K = DM, N = DM;
  short (*As)[32] = (short(*)[32])smem;            // 8 KB
  short (*Bs)[32] = (short(*)[32])(smem + 8192);   // 4 KB
  const int tid = threadIdx.x, lane = tid & 63, wid = tid >> 6;
  const int row0 = by * 128, col0 = bx * 64;

  const int sr = tid >> 2, sk = (tid & 3) * 8;
  const short* Ag0 = A + (size_t)(row0 + sr) * K + sk;
  const short* Bg0 = Bt + (size_t)(col0 + sr) * K + sk;
  short* AsL = &As[0][0] + tid * 8;
  short* BsL = &Bs[0][0] + tid * 8;

  f32x4 acc[2][4];
#pragma unroll
  for (int i = 0; i < 2; ++i)
#pragma unroll
    for (int j = 0; j < 4; ++j) acc[i][j] = (f32x4){0.f, 0.f, 0.f, 0.f};

  const int fm = wid * 32 + (lane & 15);
  const int fn = lane & 15;
  const int fk = (lane >> 4) * 8;

  for (int k0 = 0; k0 < K; k0 += 32) {
    __syncthreads();   // WAR: previous iteration / previous phase done
    stage16(Ag0 + k0, AsL);
    stage16(Ag0 + (size_t)64 * K + k0, AsL + 2048);
    stage16(Bg0 + k0, BsL);
    __syncthreads();
    bf16x8 af[2], bf[4];
#pragma unroll
    for (int t = 0; t < 2; ++t) af[t] = *(const bf16x8*)&As[fm + t * 16][fk];
#pragma unroll
    for (int t = 0; t < 4; ++t) bf[t] = *(const bf16x8*)&Bs[t * 16 + fn][fk];
#pragma unroll
    for (int im = 0; im < 2; ++im)
#pragma unroll
      for (int jn = 0; jn < 4; ++jn)
        acc[im][jn] = __builtin_amdgcn_mfma_f32_16x16x32_bf16(af[im], bf[jn], acc[im][jn], 0, 0, 0);
  }

  const int crow = (lane >> 4) * 4, ccol = lane & 15;
#pragma unroll
  for (int im = 0; im < 2; ++im)
#pragma unroll
    for (int jn = 0; jn < 4; ++jn) {
      float* Cp = C + (size_t)(row0 + wid * 32 + im * 16 + crow) * N
                    + col0 + jn * 16 + ccol;
#pragma unroll
      for (int r = 0; r < 4; ++r) Cp[(size_t)r * N] = acc[im][jn][r];
    }
}

// ============================================================================
// Fused cooperative kernel — all phases grid-stride, any grid size correct.
// ============================================================================
__global__ __launch_bounds__(256, 2) void fused_all(
    const float* __restrict__ x,  const float* __restrict__ Wq,
    const float* __restrict__ Wk, const float* __restrict__ Wv,
    const float* __restrict__ Wo, float* __restrict__ out,
    short* __restrict__ xb,   short* __restrict__ WtAll,
    short* __restrict__ qb,   short* __restrict__ kb,
    short* __restrict__ kT,   short* __restrict__ vT,
    short* __restrict__ Spre, short* __restrict__ aob) {
  cg::grid_group grid = cg::this_grid();
  __shared__ __align__(16) char smem[SMEMB];
  const int bid = blockIdx.x, gsz = gridDim.x;

  for (int u = bid; u < 1280; u += gsz)
    dev_prep_unit(u, x, Wq, Wk, Wv, Wo, xb, WtAll, smem);
  __threadfence();
  grid.sync();

  for (int u = bid; u < 768; u += gsz)
    dev_qkv_tile(u % 24, u / 24, xb, WtAll, qb, kb, kT, vT, smem);
  __threadfence();
  grid.sync();

  for (int u = bid; u < 128; u += gsz)
    dev_state_unit(u, kT, vT, Spre);
  __threadfence();
  grid.sync();

  for (int u = bid; u < 1024; u += gsz)
    dev_intra_unit(u, qb, kb, vT, Spre, aob, smem);
  __threadfence();
  grid.sync();

  for (int u = bid; u < 512; u += gsz)
    dev_out_tile(u & 15, u >> 4, aob, WtAll + (size_t)3 * DM * DM, out, smem);
}

// ============================================================================
// Standalone fallback kernels (same bodies).
// ============================================================================
__global__ __launch_bounds__(256) void k_prep(const float* x, const float* Wq,
                                              const float* Wk, const float* Wv,
                                              const float* Wo, short* xb, short* WtAll) {
  __shared__ __align__(16) char smem[SMEMB];
  dev_prep_unit(blockIdx.x, x, Wq, Wk, Wv, Wo, xb, WtAll, smem);
}
__global__ __launch_bounds__(256) void k_qkv(const short* xb, const short* WtAll,
                                             short* qb, short* kb, short* kT, short* vT) {
  __shared__ __align__(16) char smem[SMEMB];
  dev_qkv_tile(blockIdx.x % 24, blockIdx.x / 24, xb, WtAll, qb, kb, kT, vT, smem);
}
__global__ __launch_bounds__(256) void k_scan(const short* kT, const short* vT, short* Spre) {
  dev_state_unit(blockIdx.x, kT, vT, Spre);
}
__global__ __launch_bounds__(256) void k_intra(const short* qb, const short* kb,
                                               const short* vT, const short* Spre, short* aob) {
  __shared__ __align__(16) char smem[SMEMB];
  dev_intra_unit(blockIdx.x, qb, kb, vT, Spre, aob, smem);
}
__global__ __launch_bounds__(256) void k_out(const short* aob, const short* WoT, float* out) {
  __shared__ __align__(16) char smem[SMEMB];
  dev_out_tile(blockIdx.x & 15, blockIdx.x >> 4, aob, WoT, out, smem);
}

// ---------------------------------------------------------------------------
extern "C" void kernel_launch(void* const* d_in, const int* in_sizes, int n_in,
                              void* d_out, int out_size, void* d_ws, size_t ws_size,
                              hipStream_t stream) {
  const float* x  = (const float*)d_in[0];
  const float* Wq = (const float*)d_in[1];
  const float* Wk = (const float*)d_in[2];
  const float* Wv = (const float*)d_in[3];
  const float* Wo = (const float*)d_in[4];
  float* out = (float*)d_out;

  char* ws = (char*)d_ws;
  short* xb    = (short*)ws;  ws += (size_t)MR * DM * 2;     // 8 MB
  short* WtAll = (short*)ws;  ws += (size_t)4 * DM * DM * 2; // 8 MB
  short* qb    = (short*)ws;  ws += (size_t)MR * DM * 2;     // 8 MB
  short* kb    = (short*)ws;  ws += (size_t)MR * DM * 2;     // 8 MB
  short* kT    = (short*)ws;  ws += (size_t)MR * DM * 2;     // 8 MB
  short* vT    = (short*)ws;  ws += (size_t)MR * DM * 2;     // 8 MB
  short* Spre  = (short*)ws;  ws += (size_t)MR * DM * 2;     // 8 MB
  short* aob   = (short*)ws;  ws += (size_t)MR * DM * 2;     // 8 MB
  short* WoT   = WtAll + (size_t)3 * DM * DM;

  // Size the cooperative grid from actual occupancy (deterministic; avoids
  // R7's silent hipErrorCooperativeLaunchTooLarge at the theoretical max).
  int occ = 0;
  hipError_t eq = hipOccupancyMaxActiveBlocksPerMultiprocessor(
      &occ, (const void*)fused_all, 256, 0);
  bool coop_ok = (eq == hipSuccess) && (occ >= 2);

  if (coop_ok) {
    int nblk = occ * 256;
    if (nblk > 768) nblk = 768;
    void* kargs[] = {(void*)&x,  (void*)&Wq,  (void*)&Wk,   (void*)&Wv,
                     (void*)&Wo, (void*)&out, (void*)&xb,   (void*)&WtAll,
                     (void*)&qb, (void*)&kb,  (void*)&kT,   (void*)&vT,
                     (void*)&Spre, (void*)&aob};
    hipError_t el = hipLaunchCooperativeKernel((void*)fused_all, dim3(nblk),
                                               dim3(256), kargs, 0, stream);
    if (el == hipSuccess) return;
  }

  // Fallback: proven 5-kernel path (same device bodies).
  k_prep<<<1280, 256, 0, stream>>>(x, Wq, Wk, Wv, Wo, xb, WtAll);
  k_qkv<<<768, 256, 0, stream>>>(xb, WtAll, qb, kb, kT, vT);
  k_scan<<<128, 256, 0, stream>>>(kT, vT, Spre);
  k_intra<<<1024, 256, 0, stream>>>(qb, kb, vT, Spre, aob);
  k_out<<<512, 256, 0, stream>>>(aob, WoT, out);
}